// Round 17
// baseline (694.122 us; speedup 1.0000x reference)
//
#include <hip/hip_runtime.h>

typedef __bf16 bf16_t;
typedef __bf16 bf16x8 __attribute__((ext_vector_type(8)));
typedef float f32x4 __attribute__((ext_vector_type(4)));
typedef unsigned long long u64;

#define TSEQ 30
#define ISZ  100
#define HSZ  256
#define NB   5120        // LSTM batch
#define BATCH 512
#define G4   1024        // 4*H
#define TILE 320         // batch cols per block
#define NBGRP 16
#define CH   10240       // elements per K=32 chunk panel: 20 nblk * 512
#define SLABX (4 * CH)   // x slab per (bgrp,t): K=128
#define SLABH (8 * CH)   // h slab per (dir,bgrp): K=256

__device__ __forceinline__ float fsig(float x)  { return 1.0f / (1.0f + __expf(-x)); }
__device__ __forceinline__ float ftanh(float x) { return 2.0f / (1.0f + __expf(-2.0f * x)) - 1.0f; }

// ---- prep: weights -> MFMA-fragment layout, fold biases ------------------
__global__ void prep_weights(const float* __restrict__ Wih_f, const float* __restrict__ Whh_f,
                             const float* __restrict__ bih_f, const float* __restrict__ bhh_f,
                             const float* __restrict__ Wih_b, const float* __restrict__ Whh_b,
                             const float* __restrict__ bih_b, const float* __restrict__ bhh_b,
                             bf16_t* __restrict__ Wf, float* __restrict__ bias)
{
    int idx = blockIdx.x * 256 + threadIdx.x;          // over 2*1024*384
    if (idx >= 2 * G4 * 384) return;
    int d = idx / (G4 * 384);
    int r = (idx / 384) % G4;
    int k = idx % 384;
    int h = r >> 2, gate = r & 3;
    int grow = gate * HSZ + h;
    const float* Wih = d ? Wih_b : Wih_f;
    const float* Whh = d ? Whh_b : Whh_f;
    float v;
    if (k < ISZ)       v = Wih[grow * ISZ + k];
    else if (k < 128)  v = 0.0f;
    else               v = Whh[grow * HSZ + (k - 128)];
    int mf = r >> 4, lr = r & 15;
    int ks = k >> 5, lq = (k >> 3) & 3, e = k & 7;
    size_t o = ((((size_t)d * 64 + mf) * 12 + ks) * 64 + lq * 16 + lr) * 8 + e;
    Wf[o] = (bf16_t)v;
    if (k == 0) {
        const float* bih = d ? bih_b : bih_f;
        const float* bhh = d ? bhh_b : bhh_f;
        bias[d * G4 + r] = bih[grow] + bhh[grow];
    }
}

// ---- prep: x -> fragment layout, chunk-contiguous ------------------------
__global__ void prep_x(const float* __restrict__ x, bf16_t* __restrict__ xBf)
{
    int idx = blockIdx.x * 256 + threadIdx.x;          // over 16*30*4*20*512
    if (idx >= NBGRP * TSEQ * SLABX) return;
    int e    = idx & 7;
    int lane = (idx >> 3) & 63;
    int i2   = idx >> 9;
    int nblk = i2 % 20; i2 /= 20;
    int ks   = i2 & 3;  i2 >>= 2;
    int t    = i2 % TSEQ;
    int bgrp = i2 / TSEQ;
    int n = bgrp * TILE + nblk * 16 + (lane & 15);
    int k = ks * 32 + (lane >> 4) * 8 + e;
    float v = (k < ISZ) ? x[(size_t)n * (TSEQ * ISZ) + t * ISZ + k] : 0.0f;
    xBf[idx] = (bf16_t)v;
}

// ---- prep: h0 -> fragment layout ping buffer -----------------------------
__global__ void prep_state(const float* __restrict__ h0, bf16_t* __restrict__ hA)
{
    int idx = blockIdx.x * 256 + threadIdx.x;          // over 2*16*8*20*512
    if (idx >= 2 * NBGRP * SLABH) return;
    int e    = idx & 7;
    int lane = (idx >> 3) & 63;
    int i2   = idx >> 9;
    int nblk = i2 % 20; i2 /= 20;
    int ksh  = i2 & 7;  i2 >>= 3;
    int bgrp = i2 & 15;
    int dir  = i2 >> 4;
    int col = bgrp * TILE + nblk * 16 + (lane & 15);
    int hid = ksh * 32 + (lane >> 4) * 8 + e;
    hA[idx] = (bf16_t)h0[((size_t)dir * NB + col) * HSZ + hid];
}

// ---- prep: c0 -> per-thread-contiguous layout (dual-chain geometry) ------
// cws[(bid*512+tid)*20 + m*10 + nf]; block bid=(msub16,bgrp16); tid: dir=tid>>8,
// wave_c=(tid&255)>>6, mw=wave_c>>1, nw=wave_c&1
__global__ void prep_c(const float* __restrict__ c0, float* __restrict__ cws)
{
    int idx = blockIdx.x * 256 + threadIdx.x;          // over 256*512*20
    if (idx >= 256 * 512 * 20) return;
    int cell = idx % 20;
    int m    = cell / 10, nf = cell % 10;
    int tid  = (idx / 20) & 511;
    int bid  = idx / (20 * 512);
    int msub = bid >> 4, bgrp = bid & 15;
    int dirc = tid >> 8;
    int ctid = tid & 255;
    int wavec = ctid >> 6, lane = ctid & 63;
    int mw = wavec >> 1, nw = wavec & 1;
    int lr = lane & 15, lq = lane >> 4;
    int col = bgrp * TILE + (nw * 10 + nf) * 16 + lr;
    int hid = msub * 16 + mw * 8 + m * 4 + lq;
    cws[idx] = c0[((size_t)dirc * NB + col) * HSZ + hid];
}

// ---- prep: transpose W1 for coalesced head ------------------------------
__global__ void prep_w1t(const float* __restrict__ W1, float* __restrict__ W1T)
{
    int idx = blockIdx.x * 256 + threadIdx.x;          // over 2560*64
    if (idx >= 2560 * 64) return;
    int k = idx / 64, j = idx % 64;
    W1T[k * 64 + j] = W1[j * 2560 + k];
}

// ---- batched per-wave wait: lanes 0..15 RMW all 16 flags in ONE op -------
__device__ __forceinline__ void batch_wait(unsigned* flags, unsigned tgt, int lane)
{
    while (true) {
        unsigned v = tgt;
        if (lane < 16)
            v = __hip_atomic_fetch_add(flags + lane * 16, 0u,
                                       __ATOMIC_RELAXED, __HIP_MEMORY_SCOPE_AGENT);
        if (__ballot(v >= tgt) == ~0ull) break;
        __builtin_amdgcn_s_sleep(8);
    }
    __builtin_amdgcn_sched_barrier(0);                 // pin h loads after the wait
}

// ---- the 30-step loop: ONE chain (4 waves), zero intra-chain coupling ----
// No __syncthreads in the loop. Gates store h directly (scattered 2B,
// L2-write-combined — r10 evidence); each wave drains vmcnt and bumps its
// chain's producer flag; consumers batch-poll all 16 flags (incl own:
// closes the sibling write-after-read hazard) in one vector RMW.
template<bool FAST>
__device__ void run_steps(const bf16_t* __restrict__ xBf,
                          bf16_t* __restrict__ hA, bf16_t* __restrict__ hB,
                          bf16_t* __restrict__ hfin,
                          const bf16_t* wL, unsigned* myflags, unsigned* ownflag,
                          float* cst, const float4* bq,
                          int dirc, int bgrp, int msub,
                          int tid, int lane, int mw, int nw, int lr, int lq)
{
    const unsigned fo = (unsigned)(nw * 10 * 512 + lane * 8);
    const bf16_t* wp = wL + ((size_t)(dirc * 4 + mw * 2) * 12) * 512 + lane * 8;
    const size_t slab = (size_t)(dirc * NBGRP + bgrp) * SLABH;

    unsigned sb[2];
#pragma unroll
    for (int m = 0; m < 2; ++m) {
        int hid = msub * 16 + mw * 8 + m * 4 + lq;
        sb[m] = (unsigned)((hid >> 5) * CH + (((hid & 31) >> 3) * 16 + lr) * 8 + (hid & 7));
    }

#pragma unroll 1
    for (int t = 0; t < TSEQ; ++t) {
        const bf16_t* hs = (t & 1) ? hB : hA;
        bf16_t*       hw = (t & 1) ? hA : hB;
        const int tx = dirc ? (TSEQ - 1 - t) : t;
        const bf16_t* xp = xBf + (size_t)(bgrp * TSEQ + tx) * SLABX + fo;
        const bf16_t* hp = hs + slab + fo;

        f32x4 acc0[10] = {}, acc1[10] = {};
        // --- x-part (K=0..127): no dependency, before any wait ---
#pragma unroll
        for (int c = 0; c < 4; ++c) {
            bf16x8 b[10];
#pragma unroll
            for (int nf = 0; nf < 10; ++nf)
                b[nf] = *(const bf16x8*)(xp + nf * 512);
            bf16x8 a0 = *(const bf16x8*)(wp + (0 * 12 + c) * 512);
            bf16x8 a1 = *(const bf16x8*)(wp + (1 * 12 + c) * 512);
#pragma unroll
            for (int nf = 0; nf < 10; ++nf) {
                acc0[nf] = __builtin_amdgcn_mfma_f32_16x16x32_bf16(a0, b[nf], acc0[nf], 0, 0, 0);
                acc1[nf] = __builtin_amdgcn_mfma_f32_16x16x32_bf16(a1, b[nf], acc1[nf], 0, 0, 0);
            }
            xp += CH;
        }

        // --- one batched wait for ALL producers of h(t) ---
        batch_wait(myflags, 4u * (unsigned)t, lane);
        if (FAST)                                      // L1 flash-inv: stale t-2 h lines
            asm volatile("buffer_inv sc0" ::: "memory");

        // --- h-part (K=128..383): 8 straight chunks, no per-chunk sync ---
#pragma unroll
        for (int c = 0; c < 8; ++c) {
            bf16x8 b[10];
#pragma unroll
            for (int nf = 0; nf < 10; ++nf) {
                const bf16_t* src = hp + nf * 512;
                if (FAST) {
                    b[nf] = *(const bf16x8*)src;       // local-XCD L2 hit
                } else {
                    union { u64 q[2]; bf16x8 v; } u;
                    u.q[0] = __hip_atomic_load((const u64*)src,       __ATOMIC_RELAXED, __HIP_MEMORY_SCOPE_AGENT);
                    u.q[1] = __hip_atomic_load((const u64*)(src + 4), __ATOMIC_RELAXED, __HIP_MEMORY_SCOPE_AGENT);
                    b[nf] = u.v;
                }
            }
            bf16x8 a0 = *(const bf16x8*)(wp + (0 * 12 + 4 + c) * 512);
            bf16x8 a1 = *(const bf16x8*)(wp + (1 * 12 + 4 + c) * 512);
#pragma unroll
            for (int nf = 0; nf < 10; ++nf) {
                acc0[nf] = __builtin_amdgcn_mfma_f32_16x16x32_bf16(a0, b[nf], acc0[nf], 0, 0, 0);
                acc1[nf] = __builtin_amdgcn_mfma_f32_16x16x32_bf16(a1, b[nf], acc1[nf], 0, 0, 0);
            }
            hp += CH;
        }

        // --- gates + state; h stored directly (no pack, no barrier) ---
        if (t < TSEQ - 1) {
            bf16_t* hwp = hw + slab;
#pragma unroll
            for (int m = 0; m < 2; ++m) {
                float4 bb = bq[m];
#pragma unroll
                for (int nf = 0; nf < 10; ++nf) {
                    f32x4 g = m ? acc1[nf] : acc0[nf];
                    float gi = fsig(g[0] + bb.x);
                    float gf = fsig(g[1] + bb.y);
                    float gz = ftanh(g[2] + bb.z);
                    float go = fsig(g[3] + bb.w);
                    float cn = gf * cst[m * 10 + nf] + gi * gz;
                    cst[m * 10 + nf] = cn;
                    bf16_t hv = (bf16_t)(go * ftanh(cn));
                    unsigned off = sb[m] + (unsigned)((nw * 10 + nf) * 512);
                    if (FAST) {
                        hwp[off] = hv;
                    } else {
                        union { bf16_t h; unsigned short u; } cv; cv.h = hv;
                        __hip_atomic_store((unsigned short*)(hwp + off), cv.u,
                                           __ATOMIC_RELAXED, __HIP_MEMORY_SCOPE_AGENT);
                    }
                }
            }
            if (FAST) asm volatile("s_waitcnt vmcnt(0)" ::: "memory");  // stores at L2
            if ((tid & 63) == 0)
                __hip_atomic_fetch_add(ownflag, 1u,
                    FAST ? __ATOMIC_RELAXED : __ATOMIC_RELEASE, __HIP_MEMORY_SCOPE_AGENT);
        } else {
            // final step: plain-layout hfin (kernel-boundary coherence for head)
#pragma unroll
            for (int m = 0; m < 2; ++m) {
                float4 bb = bq[m];
                int hid = msub * 16 + mw * 8 + m * 4 + lq;
#pragma unroll
                for (int nf = 0; nf < 10; ++nf) {
                    f32x4 g = m ? acc1[nf] : acc0[nf];
                    float gi = fsig(g[0] + bb.x);
                    float gf = fsig(g[1] + bb.y);
                    float gz = ftanh(g[2] + bb.z);
                    float go = fsig(g[3] + bb.w);
                    float cn = gf * cst[m * 10 + nf] + gi * gz;
                    float hn = go * ftanh(cn);
                    int col = bgrp * TILE + (nw * 10 + nf) * 16 + lr;
                    hfin[((size_t)dirc * NB + col) * HSZ + hid] = (bf16_t)hn;
                }
            }
        }
    }
}

// ---- persistent LSTM: dual-chain blocks, XCD-verified fast exchange ------
// 256 blocks x 512 thr, 1 block/CU (96KB LDS). bid = msub*16 + bgrp; waves
// 0-3 = dir0 chain, waves 4-7 = dir1 chain — each SIMD carries one wave of
// EACH chain, so one chain's h-wait hides under the other's compute (m114).
// Exchange group = 16 blocks sharing bgrp -> bid%8 = bgrp%8 -> one XCD
// under round-robin (runtime-verified; coherent slow path otherwise).
__global__ __launch_bounds__(512, 1)
void lstm_persist(const bf16_t* __restrict__ Wf, const float* __restrict__ bias,
                  const bf16_t* __restrict__ xBf, const float* __restrict__ cws,
                  bf16_t* __restrict__ hA, bf16_t* __restrict__ hB,
                  bf16_t* __restrict__ hfin, unsigned* __restrict__ bar,
                  unsigned* __restrict__ xccA)
{
    __shared__ __align__(16) bf16_t wL[2 * 4 * 12 * 512];  // 96KB: both dirs' W slices
    __shared__ int sFast;

    const int bid  = blockIdx.x;
    const int msub = bid >> 4;                         // 0..15 (64 gate rows per dir)
    const int bgrp = bid & 15;
    const int tid  = threadIdx.x;
    const int dirc = tid >> 8;                         // chain: 0 or 1
    const int ctid = tid & 255;
    const int wavec = ctid >> 6;                       // 0..3 within chain
    const int lane = ctid & 63;
    const int mw   = wavec >> 1;                       // 0..1
    const int nw   = wavec & 1;                        // 0..1
    const int lr   = lane & 15;
    const int lq   = lane >> 4;

    // --- stage both dirs' W slices (rows msub*64 .. +64 of each) ---
    {
        uint4* wdst = (uint4*)wL;
        for (int i = tid; i < 6144; i += 512) {
            int d = i / 3072, off = i % 3072;
            const uint4* src = (const uint4*)(Wf + ((size_t)(d * 64 + msub * 4) * 12) * 512);
            wdst[d * 3072 + off] = src[off];
        }
    }
    // --- c -> registers; bias -> registers ---
    const float* cp = cws + ((size_t)bid * 512 + tid) * 20;
    float cst[20];
#pragma unroll
    for (int i = 0; i < 5; ++i) {
        float4 v = *(const float4*)(cp + i * 4);
        cst[i * 4 + 0] = v.x; cst[i * 4 + 1] = v.y;
        cst[i * 4 + 2] = v.z; cst[i * 4 + 3] = v.w;
    }
    float4 bq[2];
#pragma unroll
    for (int m = 0; m < 2; ++m) {
        int hid = msub * 16 + mw * 8 + m * 4 + lq;
        bq[m] = *(const float4*)(bias + dirc * G4 + hid * 4);
    }

    unsigned* myflags = bar + (dirc * NBGRP + bgrp) * 256;   // 16 flags, 64B apart
    unsigned* ownflag = myflags + msub * 16;
    unsigned* gbar    = bar + 8192 + bgrp * 16;

    // --- publish XCD id, group-verify co-location (once, 16 blocks/bgrp) ---
    unsigned xcc;
    asm volatile("s_getreg_b32 %0, hwreg(HW_REG_XCC_ID)" : "=s"(xcc));
    if (tid == 0) {
        __hip_atomic_store(&xccA[bid], xcc, __ATOMIC_RELAXED, __HIP_MEMORY_SCOPE_AGENT);
        __hip_atomic_fetch_add(gbar, 1u, __ATOMIC_RELEASE, __HIP_MEMORY_SCOPE_AGENT);
        while (__hip_atomic_fetch_add(gbar, 0u, __ATOMIC_RELAXED, __HIP_MEMORY_SCOPE_AGENT) < 16u)
            __builtin_amdgcn_s_sleep(1);
        int ok = (xcc < 8u) ? 1 : 0;
        for (int m2 = 0; m2 < 16; ++m2) {
            unsigned v = __hip_atomic_load(&xccA[m2 * 16 + bgrp],
                                           __ATOMIC_RELAXED, __HIP_MEMORY_SCOPE_AGENT);
            ok &= (v == xcc) ? 1 : 0;
        }
        sFast = ok;
    }
    __syncthreads();                                   // W staged + sFast ready (only barrier)

    if (sFast)
        run_steps<true>(xBf, hA, hB, hfin, wL, myflags, ownflag, cst, bq,
                        dirc, bgrp, msub, tid, lane, mw, nw, lr, lq);
    else
        run_steps<false>(xBf, hA, hB, hfin, wL, myflags, ownflag, cst, bq,
                         dirc, bgrp, msub, tid, lane, mw, nw, lr, lq);
}

// ---- head: x_fea assembly + Linear(2560,64) + Linear(64,5) + softmax ----
__global__ __launch_bounds__(256)
void head_kernel(const bf16_t* __restrict__ hfin, const float* __restrict__ W1T,
                 const float* __restrict__ b1, const float* __restrict__ W2,
                 const float* __restrict__ b2, float* __restrict__ out)
{
    __shared__ float flat_s[2560];
    __shared__ float partial[4][64];
    __shared__ float zs[64];
    __shared__ float ls[5];
    __shared__ float es[5];
    int b = blockIdx.x, tid = threadIdx.x;
    const bf16_t* hF = hfin;
    const bf16_t* hB = hfin + (size_t)NB * HSZ;
    float* xfea = out + BATCH * 5 + (size_t)b * 2560;

    for (int j = tid; j < 2560; j += 256) {
        int s = j >> 8, c = j & 255;
        int n = b * 10 + s;
        float v = (c < 128) ? (float)hF[(size_t)n * HSZ + c] : (float)hB[(size_t)n * HSZ + c];
        flat_s[j] = v;
        xfea[j] = v;
    }
    __syncthreads();
    int j = tid & 63, q = tid >> 6;
    float sum = 0.0f;
    for (int k = q * 640; k < (q + 1) * 640; ++k) sum += flat_s[k] * W1T[k * 64 + j];
    partial[q][j] = sum;
    __syncthreads();
    if (tid < 64) zs[tid] = partial[0][tid] + partial[1][tid] + partial[2][tid] + partial[3][tid] + b1[tid];
    __syncthreads();
    if (tid < 5) {
        float l = b2[tid];
        for (int k = 0; k < 64; ++k) l += zs[k] * W2[tid * 64 + k];
        ls[tid] = l;
    }
    __syncthreads();
    if (tid < 5) {
        float m = ls[0];
        for (int k = 1; k < 5; ++k) m = fmaxf(m, ls[k]);
        es[tid] = __expf(ls[tid] - m);
    }
    __syncthreads();
    if (tid < 5) {
        float s5 = es[0] + es[1] + es[2] + es[3] + es[4];
        out[b * 5 + tid] = es[tid] / s5;
    }
}

extern "C" void kernel_launch(void* const* d_in, const int* in_sizes, int n_in,
                              void* d_out, int out_size, void* d_ws, size_t ws_size,
                              hipStream_t stream) {
    const float* x     = (const float*)d_in[0];
    const float* h0    = (const float*)d_in[1];
    const float* c0    = (const float*)d_in[2];
    const float* Wih_f = (const float*)d_in[3];
    const float* Whh_f = (const float*)d_in[4];
    const float* bih_f = (const float*)d_in[5];
    const float* bhh_f = (const float*)d_in[6];
    const float* Wih_b = (const float*)d_in[7];
    const float* Whh_b = (const float*)d_in[8];
    const float* bih_b = (const float*)d_in[9];
    const float* bhh_b = (const float*)d_in[10];
    const float* W1    = (const float*)d_in[11];
    const float* b1    = (const float*)d_in[12];
    const float* W2    = (const float*)d_in[13];
    const float* b2    = (const float*)d_in[14];
    float* out = (float*)d_out;

    uintptr_t ws = (uintptr_t)d_ws;
    bf16_t*   Wf   = (bf16_t*)(ws);                    // 1,572,864
    float*    bias = (float*)(ws + 1572864);           // 8,192
    bf16_t*   xBf  = (bf16_t*)(ws + 1581056);          // 39,321,600
    bf16_t*   hAb  = (bf16_t*)(ws + 40902656);         // 5,242,880
    bf16_t*   hBb  = (bf16_t*)(ws + 46145536);         // 5,242,880
    bf16_t*   hfin = (bf16_t*)(ws + 51388416);         // 5,242,880
    float*    W1T  = (float*)(ws + 56631296);          // 655,360
    float*    cws  = (float*)(ws + 57286656);          // 10,485,760
    unsigned* bar  = (unsigned*)(ws + 67772416);       // 36KB (flags 32KB + group bar)
    unsigned* xccA = (unsigned*)(ws + 67809280);       // 1,024 (256 u32)

    hipMemsetAsync((void*)bar, 0, 40960, stream);

    prep_weights<<<(2 * G4 * 384 + 255) / 256, 256, 0, stream>>>(
        Wih_f, Whh_f, bih_f, bhh_f, Wih_b, Whh_b, bih_b, bhh_b, Wf, bias);
    prep_x<<<(NBGRP * TSEQ * SLABX + 255) / 256, 256, 0, stream>>>(x, xBf);
    prep_state<<<(2 * NBGRP * SLABH + 255) / 256, 256, 0, stream>>>(h0, hAb);
    prep_c<<<(256 * 512 * 20 + 255) / 256, 256, 0, stream>>>(c0, cws);
    prep_w1t<<<(2560 * 64 + 255) / 256, 256, 0, stream>>>(W1, W1T);

    lstm_persist<<<256, 512, 0, stream>>>(Wf, bias, xBf, cws, hAb, hBb, hfin, bar, xccA);
    head_kernel<<<BATCH, 256, 0, stream>>>(hfin, W1T, b1, W2, b2, out);
}

// Round 18
// 641.646 us; speedup vs baseline: 1.0818x; 1.0818x over previous
//
#include <hip/hip_runtime.h>

typedef __bf16 bf16_t;
typedef __bf16 bf16x8 __attribute__((ext_vector_type(8)));
typedef float f32x4 __attribute__((ext_vector_type(4)));
typedef unsigned long long u64;

#define TSEQ 30
#define ISZ  100
#define HSZ  256
#define NB   5120        // LSTM batch
#define BATCH 512
#define G4   1024        // 4*H
#define TILE 320         // batch cols per block
#define NBGRP 16
#define CH   10240       // elements per K=32 chunk panel: 20 nblk * 512
#define SLABX (4 * CH)   // x slab per (bgrp,t): K=128
#define SLABH (8 * CH)   // h slab per (dir,bgrp): K=256

__device__ __forceinline__ float fsig(float x)  { return 1.0f / (1.0f + __expf(-x)); }
__device__ __forceinline__ float ftanh(float x) { return 2.0f / (1.0f + __expf(-2.0f * x)) - 1.0f; }

// ---- prep: weights -> MFMA-fragment layout, fold biases ------------------
__global__ void prep_weights(const float* __restrict__ Wih_f, const float* __restrict__ Whh_f,
                             const float* __restrict__ bih_f, const float* __restrict__ bhh_f,
                             const float* __restrict__ Wih_b, const float* __restrict__ Whh_b,
                             const float* __restrict__ bih_b, const float* __restrict__ bhh_b,
                             bf16_t* __restrict__ Wf, float* __restrict__ bias)
{
    int idx = blockIdx.x * 256 + threadIdx.x;          // over 2*1024*384
    if (idx >= 2 * G4 * 384) return;
    int d = idx / (G4 * 384);
    int r = (idx / 384) % G4;
    int k = idx % 384;
    int h = r >> 2, gate = r & 3;
    int grow = gate * HSZ + h;
    const float* Wih = d ? Wih_b : Wih_f;
    const float* Whh = d ? Whh_b : Whh_f;
    float v;
    if (k < ISZ)       v = Wih[grow * ISZ + k];
    else if (k < 128)  v = 0.0f;
    else               v = Whh[grow * HSZ + (k - 128)];
    int mf = r >> 4, lr = r & 15;
    int ks = k >> 5, lq = (k >> 3) & 3, e = k & 7;
    size_t o = ((((size_t)d * 64 + mf) * 12 + ks) * 64 + lq * 16 + lr) * 8 + e;
    Wf[o] = (bf16_t)v;
    if (k == 0) {
        const float* bih = d ? bih_b : bih_f;
        const float* bhh = d ? bhh_b : bhh_f;
        bias[d * G4 + r] = bih[grow] + bhh[grow];
    }
}

// ---- prep: x -> fragment layout, chunk-contiguous ------------------------
__global__ void prep_x(const float* __restrict__ x, bf16_t* __restrict__ xBf)
{
    int idx = blockIdx.x * 256 + threadIdx.x;          // over 16*30*4*20*512
    if (idx >= NBGRP * TSEQ * SLABX) return;
    int e    = idx & 7;
    int lane = (idx >> 3) & 63;
    int i2   = idx >> 9;
    int nblk = i2 % 20; i2 /= 20;
    int ks   = i2 & 3;  i2 >>= 2;
    int t    = i2 % TSEQ;
    int bgrp = i2 / TSEQ;
    int n = bgrp * TILE + nblk * 16 + (lane & 15);
    int k = ks * 32 + (lane >> 4) * 8 + e;
    float v = (k < ISZ) ? x[(size_t)n * (TSEQ * ISZ) + t * ISZ + k] : 0.0f;
    xBf[idx] = (bf16_t)v;
}

// ---- prep: h0 -> fragment layout ping buffer -----------------------------
__global__ void prep_state(const float* __restrict__ h0, bf16_t* __restrict__ hA)
{
    int idx = blockIdx.x * 256 + threadIdx.x;          // over 2*16*8*20*512
    if (idx >= 2 * NBGRP * SLABH) return;
    int e    = idx & 7;
    int lane = (idx >> 3) & 63;
    int i2   = idx >> 9;
    int nblk = i2 % 20; i2 /= 20;
    int ksh  = i2 & 7;  i2 >>= 3;
    int bgrp = i2 & 15;
    int dir  = i2 >> 4;
    int col = bgrp * TILE + nblk * 16 + (lane & 15);
    int hid = ksh * 32 + (lane >> 4) * 8 + e;
    hA[idx] = (bf16_t)h0[((size_t)dir * NB + col) * HSZ + hid];
}

// ---- prep: c0 -> per-thread-contiguous layout ----------------------------
__global__ void prep_c(const float* __restrict__ c0, float* __restrict__ cws)
{
    int idx = blockIdx.x * 256 + threadIdx.x;          // over 256*512*20
    if (idx >= 256 * 512 * 20) return;
    int m   = idx & 3;
    int nf  = (idx >> 2) % 5;
    int tid = (idx / 20) & 511;
    int bid = idx / (20 * 512);
    int msub = bid >> 5, dir = (bid >> 4) & 1, bgrp = bid & 15;
    int lane = tid & 63, mw = (tid >> 6) >> 2, nw = (tid >> 6) & 3;
    int lr = lane & 15, lq = lane >> 4;
    int col = bgrp * TILE + nw * 80 + nf * 16 + lr;
    int hid = msub * 32 + mw * 16 + m * 4 + lq;
    cws[idx] = c0[((size_t)dir * NB + col) * HSZ + hid];
}

// ---- prep: transpose W1 for coalesced head ------------------------------
__global__ void prep_w1t(const float* __restrict__ W1, float* __restrict__ W1T)
{
    int idx = blockIdx.x * 256 + threadIdx.x;          // over 2560*64
    if (idx >= 2560 * 64) return;
    int k = idx / 64, j = idx % 64;
    W1T[k * 64 + j] = W1[j * 2560 + k];
}

// ---- batched per-wave wait: lanes 0..7 RMW all 8 producer flags at once --
__device__ __forceinline__ void batch_wait8(unsigned* flags, unsigned tgt, int lane)
{
    while (true) {
        unsigned v = tgt;
        if (lane < 8)
            v = __hip_atomic_fetch_add(flags + lane * 16, 0u,
                                       __ATOMIC_RELAXED, __HIP_MEMORY_SCOPE_AGENT);
        if (__ballot(v >= tgt) == ~0ull) break;
        __builtin_amdgcn_s_sleep(4);
    }
    __builtin_amdgcn_sched_barrier(0);                 // pin h loads after the wait
}

// ---- the 30-step loop: ZERO __syncthreads, wave-autonomous epilogue ------
// pkL segment [(nw*5+nf)*512 + mw*256, +256) is written exclusively by wave
// (mw,nw): each wave packs its own segments, lgkmcnt-drains, reads them back
// (8B/lane), stores coalesced to the slab, vmcnt-drains, bumps the block
// flag itself. Consumers batch-poll all 8 producer flags (target 8t) once,
// after the x-part. WAR-safe at wave granularity: a wave's t+1 store follows
// its t+1 wait (needs all waves' t stores, which follow their t reads).
template<bool FAST>
__device__ void run_steps(const bf16_t* __restrict__ xBf,
                          bf16_t* __restrict__ hA, bf16_t* __restrict__ hB,
                          bf16_t* __restrict__ hfin,
                          const bf16_t* wL, bf16_t* pkL,
                          unsigned* flags, unsigned* ownflag,
                          f32x4* c4, const float4* bq,
                          int dir, int bgrp, int msub,
                          int tid, int lane, int mw, int nw, int lr, int lq)
{
    const unsigned fo = (unsigned)(nw * 5 * 512 + lane * 8);   // per-lane frag offset
    const bf16_t* wp = wL + (mw * 4 * 12) * 512 + lane * 8;    // a-base (ds imm-foldable)
    const size_t slab = (size_t)(dir * NBGRP + bgrp) * SLABH;

#pragma unroll 1
    for (int t = 0; t < TSEQ; ++t) {
        const bf16_t* hs = (t & 1) ? hB : hA;
        bf16_t*       hw = (t & 1) ? hA : hB;
        const int tx = dir ? (TSEQ - 1 - t) : t;
        const bf16_t* xp = xBf + (size_t)(bgrp * TSEQ + tx) * SLABX + fo;
        const bf16_t* hp = hs + slab + fo;

        f32x4 acc[4][5] = {};
        // --- x-part (K=0..127): no h dependency, before the wait ---
#pragma unroll
        for (int c = 0; c < 4; ++c) {
            bf16x8 b[5];
#pragma unroll
            for (int nf = 0; nf < 5; ++nf)
                b[nf] = *(const bf16x8*)(xp + nf * 512);
            bf16x8 a[4];
#pragma unroll
            for (int m = 0; m < 4; ++m)
                a[m] = *(const bf16x8*)(wp + (m * 12 + c) * 512);
#pragma unroll
            for (int m = 0; m < 4; ++m)
#pragma unroll
                for (int nf = 0; nf < 5; ++nf)
                    acc[m][nf] = __builtin_amdgcn_mfma_f32_16x16x32_bf16(a[m], b[nf], acc[m][nf], 0, 0, 0);
            xp += CH;
        }

        // --- one batched wait for all 8 producers of h(t) (incl. own) ---
        batch_wait8(flags, 8u * (unsigned)t, lane);
        if (FAST)                                      // L1 flash-inv: stale t-2 h lines
            asm volatile("buffer_inv sc0" ::: "memory");

        // --- h-part (K=128..383): 8 straight chunks ---
#pragma unroll
        for (int c = 0; c < 8; ++c) {
            bf16x8 b[5];
#pragma unroll
            for (int nf = 0; nf < 5; ++nf) {
                const bf16_t* src = hp + nf * 512;
                if (FAST) {
                    b[nf] = *(const bf16x8*)src;       // local-XCD L2 hit
                } else {
                    union { u64 q[2]; bf16x8 v; } u;
                    u.q[0] = __hip_atomic_load((const u64*)src,       __ATOMIC_RELAXED, __HIP_MEMORY_SCOPE_AGENT);
                    u.q[1] = __hip_atomic_load((const u64*)(src + 4), __ATOMIC_RELAXED, __HIP_MEMORY_SCOPE_AGENT);
                    b[nf] = u.v;
                }
            }
            bf16x8 a[4];
#pragma unroll
            for (int m = 0; m < 4; ++m)
                a[m] = *(const bf16x8*)(wp + (m * 12 + c + 4) * 512);
#pragma unroll
            for (int m = 0; m < 4; ++m)
#pragma unroll
                for (int nf = 0; nf < 5; ++nf)
                    acc[m][nf] = __builtin_amdgcn_mfma_f32_16x16x32_bf16(a[m], b[nf], acc[m][nf], 0, 0, 0);
            hp += CH;
        }

        // --- gates + state; wave-autonomous pack->readback->store->signal ---
        if (t < TSEQ - 1) {
#pragma unroll
            for (int m = 0; m < 4; ++m) {
                float4 bb = bq[m];
                int hl = mw * 16 + m * 4 + lq;
#pragma unroll
                for (int nf = 0; nf < 5; ++nf) {
                    f32x4 g = acc[m][nf];
                    float gi = fsig(g[0] + bb.x);
                    float gf = fsig(g[1] + bb.y);
                    float gz = ftanh(g[2] + bb.z);
                    float go = fsig(g[3] + bb.w);
                    float cn = gf * c4[nf][m] + gi * gz;
                    c4[nf][m] = cn;
                    pkL[(nw * 5 + nf) * 512 + ((hl >> 3) * 16 + lr) * 8 + (hl & 7)]
                        = (bf16_t)(go * ftanh(cn));
                }
            }
            asm volatile("s_waitcnt lgkmcnt(0)" ::: "memory");  // my pack writes landed
            __builtin_amdgcn_sched_barrier(0);
            // readback MY segments (5 x 8B/lane) and store coalesced
            bf16_t* dstb = hw + slab + (size_t)msub * CH;
#pragma unroll
            for (int nf = 0; nf < 5; ++nf) {
                unsigned so = (unsigned)((nw * 5 + nf) * 512 + mw * 256 + lane * 4);
                uint2 v = *(const uint2*)(pkL + so);
                if (FAST) {
                    *(uint2*)(dstb + so) = v;
                } else {
                    union { uint2 d; u64 q; } cv; cv.d = v;
                    __hip_atomic_store((u64*)(dstb + so), cv.q,
                                       __ATOMIC_RELAXED, __HIP_MEMORY_SCOPE_AGENT);
                }
            }
            asm volatile("s_waitcnt vmcnt(0)" ::: "memory");    // stores at L2/MALL
            if ((tid & 63) == 0)
                __hip_atomic_fetch_add(ownflag, 1u,
                    FAST ? __ATOMIC_RELAXED : __ATOMIC_RELEASE, __HIP_MEMORY_SCOPE_AGENT);
        } else {
            // final step: plain-layout hfin (kernel-boundary coherence for head)
#pragma unroll
            for (int m = 0; m < 4; ++m) {
                float4 bb = bq[m];
#pragma unroll
                for (int nf = 0; nf < 5; ++nf) {
                    f32x4 g = acc[m][nf];
                    float gi = fsig(g[0] + bb.x);
                    float gf = fsig(g[1] + bb.y);
                    float gz = ftanh(g[2] + bb.z);
                    float go = fsig(g[3] + bb.w);
                    float cn = gf * c4[nf][m] + gi * gz;
                    float hn = go * ftanh(cn);
                    int col = bgrp * TILE + nw * 80 + nf * 16 + lr;
                    int hid = msub * 32 + mw * 16 + m * 4 + lq;
                    hfin[((size_t)dir * NB + col) * HSZ + hid] = (bf16_t)hn;
                }
            }
        }
    }
}

// ---- persistent LSTM: XCD-verified fast exchange, wave-autonomous --------
__global__ __launch_bounds__(512, 1)
void lstm_persist(const bf16_t* __restrict__ Wf, const float* __restrict__ bias,
                  const bf16_t* __restrict__ xBf, const float* __restrict__ cws,
                  bf16_t* __restrict__ hA, bf16_t* __restrict__ hB,
                  bf16_t* __restrict__ hfin, unsigned* __restrict__ bar,
                  unsigned* __restrict__ xccA)
{
    __shared__ __align__(16) bf16_t wL[8 * 12 * 512];  // 96KB W slice
    __shared__ __align__(16) bf16_t pkL[CH];           // 20KB h pack buffer
    __shared__ int sFast;

    const int bid  = blockIdx.x;
    const int msub = bid >> 5;
    const int dir  = (bid >> 4) & 1;
    const int bgrp = bid & 15;
    const int tid  = threadIdx.x;
    const int lane = tid & 63;
    const int mw   = (tid >> 6) >> 2;                  // 0..1
    const int nw   = (tid >> 6) & 3;                   // 0..3
    const int lr   = lane & 15;
    const int lq   = lane >> 4;

    // --- stage W slice once; c -> registers; bias -> registers ---
    {
        const uint4* wsrc = (const uint4*)(Wf + ((size_t)dir * 64 + msub * 8) * 12 * 512);
        uint4* wdst = (uint4*)wL;
        for (int i = tid; i < 6144; i += 512) wdst[i] = wsrc[i];
    }
    const float* cp = cws + ((size_t)bid * 512 + tid) * 20;
    f32x4 c4[5];
#pragma unroll
    for (int nf = 0; nf < 5; ++nf) c4[nf] = *(const f32x4*)(cp + nf * 4);
    float4 bq[4];
#pragma unroll
    for (int m = 0; m < 4; ++m)
        bq[m] = *(const float4*)(bias + dir * G4 + (msub * 32 + mw * 16 + m * 4 + lq) * 4);

    unsigned* flags   = bar + (dir * NBGRP + bgrp) * 128;    // 8 flags, 64B apart
    unsigned* ownflag = flags + msub * 16;
    unsigned* mybarX  = bar + 32 * 128 + (dir * NBGRP + bgrp) * 16;

    // --- publish XCD id, group-verify co-location (once) ---
    unsigned xcc;
    asm volatile("s_getreg_b32 %0, hwreg(HW_REG_XCC_ID)" : "=s"(xcc));
    if (tid == 0) {
        __hip_atomic_store(&xccA[bid], xcc, __ATOMIC_RELAXED, __HIP_MEMORY_SCOPE_AGENT);
        __hip_atomic_fetch_add(mybarX, 1u, __ATOMIC_RELEASE, __HIP_MEMORY_SCOPE_AGENT);
        while (__hip_atomic_fetch_add(mybarX, 0u, __ATOMIC_RELAXED, __HIP_MEMORY_SCOPE_AGENT) < 8u)
            __builtin_amdgcn_s_sleep(1);
        int ok = (xcc < 8u) ? 1 : 0;
        for (int m2 = 0; m2 < 8; ++m2) {
            unsigned v = __hip_atomic_load(&xccA[m2 * 32 + dir * 16 + bgrp],
                                           __ATOMIC_RELAXED, __HIP_MEMORY_SCOPE_AGENT);
            ok &= (v == xcc) ? 1 : 0;
        }
        sFast = ok;
    }
    __syncthreads();                                   // W staged + sFast ready (only barrier)

    if (sFast)
        run_steps<true>(xBf, hA, hB, hfin, wL, pkL, flags, ownflag, c4, bq,
                        dir, bgrp, msub, tid, lane, mw, nw, lr, lq);
    else
        run_steps<false>(xBf, hA, hB, hfin, wL, pkL, flags, ownflag, c4, bq,
                         dir, bgrp, msub, tid, lane, mw, nw, lr, lq);
}

// ---- head: x_fea assembly + Linear(2560,64) + Linear(64,5) + softmax ----
__global__ __launch_bounds__(256)
void head_kernel(const bf16_t* __restrict__ hfin, const float* __restrict__ W1T,
                 const float* __restrict__ b1, const float* __restrict__ W2,
                 const float* __restrict__ b2, float* __restrict__ out)
{
    __shared__ float flat_s[2560];
    __shared__ float partial[4][64];
    __shared__ float zs[64];
    __shared__ float ls[5];
    __shared__ float es[5];
    int b = blockIdx.x, tid = threadIdx.x;
    const bf16_t* hF = hfin;
    const bf16_t* hB = hfin + (size_t)NB * HSZ;
    float* xfea = out + BATCH * 5 + (size_t)b * 2560;

    for (int j = tid; j < 2560; j += 256) {
        int s = j >> 8, c = j & 255;
        int n = b * 10 + s;
        float v = (c < 128) ? (float)hF[(size_t)n * HSZ + c] : (float)hB[(size_t)n * HSZ + c];
        flat_s[j] = v;
        xfea[j] = v;
    }
    __syncthreads();
    int j = tid & 63, q = tid >> 6;
    float sum = 0.0f;
    for (int k = q * 640; k < (q + 1) * 640; ++k) sum += flat_s[k] * W1T[k * 64 + j];
    partial[q][j] = sum;
    __syncthreads();
    if (tid < 64) zs[tid] = partial[0][tid] + partial[1][tid] + partial[2][tid] + partial[3][tid] + b1[tid];
    __syncthreads();
    if (tid < 5) {
        float l = b2[tid];
        for (int k = 0; k < 64; ++k) l += zs[k] * W2[tid * 64 + k];
        ls[tid] = l;
    }
    __syncthreads();
    if (tid < 5) {
        float m = ls[0];
        for (int k = 1; k < 5; ++k) m = fmaxf(m, ls[k]);
        es[tid] = __expf(ls[tid] - m);
    }
    __syncthreads();
    if (tid < 5) {
        float s5 = es[0] + es[1] + es[2] + es[3] + es[4];
        out[b * 5 + tid] = es[tid] / s5;
    }
}

extern "C" void kernel_launch(void* const* d_in, const int* in_sizes, int n_in,
                              void* d_out, int out_size, void* d_ws, size_t ws_size,
                              hipStream_t stream) {
    const float* x     = (const float*)d_in[0];
    const float* h0    = (const float*)d_in[1];
    const float* c0    = (const float*)d_in[2];
    const float* Wih_f = (const float*)d_in[3];
    const float* Whh_f = (const float*)d_in[4];
    const float* bih_f = (const float*)d_in[5];
    const float* bhh_f = (const float*)d_in[6];
    const float* Wih_b = (const float*)d_in[7];
    const float* Whh_b = (const float*)d_in[8];
    const float* bih_b = (const float*)d_in[9];
    const float* bhh_b = (const float*)d_in[10];
    const float* W1    = (const float*)d_in[11];
    const float* b1    = (const float*)d_in[12];
    const float* W2    = (const float*)d_in[13];
    const float* b2    = (const float*)d_in[14];
    float* out = (float*)d_out;

    uintptr_t ws = (uintptr_t)d_ws;
    bf16_t*   Wf   = (bf16_t*)(ws);                    // 1,572,864
    float*    bias = (float*)(ws + 1572864);           // 8,192
    bf16_t*   xBf  = (bf16_t*)(ws + 1581056);          // 39,321,600
    bf16_t*   hAb  = (bf16_t*)(ws + 40902656);         // 5,242,880
    bf16_t*   hBb  = (bf16_t*)(ws + 46145536);         // 5,242,880
    bf16_t*   hfin = (bf16_t*)(ws + 51388416);         // 5,242,880
    float*    W1T  = (float*)(ws + 56631296);          // 655,360
    float*    cws  = (float*)(ws + 57286656);          // 10,485,760
    unsigned* bar  = (unsigned*)(ws + 67772416);       // 18,432 (flags 16KB + xcd-bar 2KB)
    unsigned* xccA = (unsigned*)(ws + 67790848);       // 1,024 (256 u32)

    hipMemsetAsync((void*)bar, 0, 18432, stream);

    prep_weights<<<(2 * G4 * 384 + 255) / 256, 256, 0, stream>>>(
        Wih_f, Whh_f, bih_f, bhh_f, Wih_b, Whh_b, bih_b, bhh_b, Wf, bias);
    prep_x<<<(NBGRP * TSEQ * SLABX + 255) / 256, 256, 0, stream>>>(x, xBf);
    prep_state<<<(2 * NBGRP * SLABH + 255) / 256, 256, 0, stream>>>(h0, hAb);
    prep_c<<<(256 * 512 * 20 + 255) / 256, 256, 0, stream>>>(c0, cws);
    prep_w1t<<<(2560 * 64 + 255) / 256, 256, 0, stream>>>(W1, W1T);

    lstm_persist<<<256, 512, 0, stream>>>(Wf, bias, xBf, cws, hAb, hBb, hfin, bar, xccA);
    head_kernel<<<BATCH, 256, 0, stream>>>(hfin, W1T, b1, W2, b2, out);
}

// Round 19
// 573.476 us; speedup vs baseline: 1.2104x; 1.1189x over previous
//
#include <hip/hip_runtime.h>

typedef __bf16 bf16_t;
typedef __bf16 bf16x8 __attribute__((ext_vector_type(8)));
typedef float f32x4 __attribute__((ext_vector_type(4)));
typedef unsigned long long u64;

#define TSEQ 30
#define ISZ  100
#define HSZ  256
#define NB   5120        // LSTM batch
#define BATCH 512
#define G4   1024        // 4*H
#define TILE 320         // batch cols per block
#define NBGRP 16
#define CH   10240       // elements per K=32 chunk panel: 20 nblk * 512
#define SLABX (4 * CH)   // x slab per (bgrp,t): K=128
#define SLABH (8 * CH)   // h slab per (dir,bgrp): K=256

__device__ __forceinline__ float fsig(float x)  { return 1.0f / (1.0f + __expf(-x)); }
__device__ __forceinline__ float ftanh(float x) { return 2.0f / (1.0f + __expf(-2.0f * x)) - 1.0f; }

// ---- prep: weights -> MFMA-fragment layout, fold biases ------------------
__global__ void prep_weights(const float* __restrict__ Wih_f, const float* __restrict__ Whh_f,
                             const float* __restrict__ bih_f, const float* __restrict__ bhh_f,
                             const float* __restrict__ Wih_b, const float* __restrict__ Whh_b,
                             const float* __restrict__ bih_b, const float* __restrict__ bhh_b,
                             bf16_t* __restrict__ Wf, float* __restrict__ bias)
{
    int idx = blockIdx.x * 256 + threadIdx.x;          // over 2*1024*384
    if (idx >= 2 * G4 * 384) return;
    int d = idx / (G4 * 384);
    int r = (idx / 384) % G4;
    int k = idx % 384;
    int h = r >> 2, gate = r & 3;
    int grow = gate * HSZ + h;
    const float* Wih = d ? Wih_b : Wih_f;
    const float* Whh = d ? Whh_b : Whh_f;
    float v;
    if (k < ISZ)       v = Wih[grow * ISZ + k];
    else if (k < 128)  v = 0.0f;
    else               v = Whh[grow * HSZ + (k - 128)];
    int mf = r >> 4, lr = r & 15;
    int ks = k >> 5, lq = (k >> 3) & 3, e = k & 7;
    size_t o = ((((size_t)d * 64 + mf) * 12 + ks) * 64 + lq * 16 + lr) * 8 + e;
    Wf[o] = (bf16_t)v;
    if (k == 0) {
        const float* bih = d ? bih_b : bih_f;
        const float* bhh = d ? bhh_b : bhh_f;
        bias[d * G4 + r] = bih[grow] + bhh[grow];
    }
}

// ---- prep: x -> fragment layout, chunk-contiguous ------------------------
__global__ void prep_x(const float* __restrict__ x, bf16_t* __restrict__ xBf)
{
    int idx = blockIdx.x * 256 + threadIdx.x;          // over 16*30*4*20*512
    if (idx >= NBGRP * TSEQ * SLABX) return;
    int e    = idx & 7;
    int lane = (idx >> 3) & 63;
    int i2   = idx >> 9;
    int nblk = i2 % 20; i2 /= 20;
    int ks   = i2 & 3;  i2 >>= 2;
    int t    = i2 % TSEQ;
    int bgrp = i2 / TSEQ;
    int n = bgrp * TILE + nblk * 16 + (lane & 15);
    int k = ks * 32 + (lane >> 4) * 8 + e;
    float v = (k < ISZ) ? x[(size_t)n * (TSEQ * ISZ) + t * ISZ + k] : 0.0f;
    xBf[idx] = (bf16_t)v;
}

// ---- prep: h0 -> fragment layout ping buffer -----------------------------
__global__ void prep_state(const float* __restrict__ h0, bf16_t* __restrict__ hA)
{
    int idx = blockIdx.x * 256 + threadIdx.x;          // over 2*16*8*20*512
    if (idx >= 2 * NBGRP * SLABH) return;
    int e    = idx & 7;
    int lane = (idx >> 3) & 63;
    int i2   = idx >> 9;
    int nblk = i2 % 20; i2 /= 20;
    int ksh  = i2 & 7;  i2 >>= 3;
    int bgrp = i2 & 15;
    int dir  = i2 >> 4;
    int col = bgrp * TILE + nblk * 16 + (lane & 15);
    int hid = ksh * 32 + (lane >> 4) * 8 + e;
    hA[idx] = (bf16_t)h0[((size_t)dir * NB + col) * HSZ + hid];
}

// ---- prep: c0 -> per-thread-contiguous layout (dual-dir geometry) --------
// cws[(bid*512+tid)*20 + cell], cell = d*10 + m*5 + nf; bid = msub*16+bgrp
__global__ void prep_c(const float* __restrict__ c0, float* __restrict__ cws)
{
    int idx = blockIdx.x * 256 + threadIdx.x;          // over 256*512*20
    if (idx >= 256 * 512 * 20) return;
    int cell = idx % 20;
    int d  = cell / 10;
    int m  = (cell % 10) / 5;
    int nf = cell % 5;
    int tid = (idx / 20) & 511;
    int bid = idx / (20 * 512);
    int msub = bid >> 4, bgrp = bid & 15;
    int wave = tid >> 6, lane = tid & 63;
    int mw = wave >> 2, nw = wave & 3;
    int lr = lane & 15, lq = lane >> 4;
    int col = bgrp * TILE + nw * 80 + nf * 16 + lr;
    int hid = msub * 16 + mw * 8 + m * 4 + lq;
    cws[idx] = c0[((size_t)d * NB + col) * HSZ + hid];
}

// ---- prep: transpose W1 for coalesced head ------------------------------
__global__ void prep_w1t(const float* __restrict__ W1, float* __restrict__ W1T)
{
    int idx = blockIdx.x * 256 + threadIdx.x;          // over 2560*64
    if (idx >= 2560 * 64) return;
    int k = idx / 64, j = idx % 64;
    W1T[k * 64 + j] = W1[j * 2560 + k];
}

// ---- batched per-wave wait: lanes 0..15 RMW all 16 producer flags --------
__device__ __forceinline__ void batch_wait16(unsigned* flags, unsigned tgt, int lane)
{
    while (true) {
        unsigned v = tgt;
        if (lane < 16)
            v = __hip_atomic_fetch_add(flags + lane * 16, 0u,
                                       __ATOMIC_RELAXED, __HIP_MEMORY_SCOPE_AGENT);
        if (__ballot(v >= tgt) == ~0ull) break;
        __builtin_amdgcn_s_sleep(2);
    }
    __builtin_amdgcn_sched_barrier(0);                 // pin h loads after the wait
}

// ---- the 30-step loop: TWO independent recurrences, time-interleaved -----
// Per step: [wait(d0) -> d0 MFMA+gates+store+signal] -> [wait(d1) -> d1 ...].
// Dir0's signal ages through dir1's whole ~5.5µs phase before dir0's next
// wait -> exchange latency fully hidden by real work (r13-r18 lesson: the
// cost was latency aging, not skew). Waits run BEFORE the dir's MFMA, so
// acc (40 regs) is never live across a wait (r14 spill rule).
template<bool FAST>
__device__ void run_steps(const bf16_t* __restrict__ xBf,
                          bf16_t* __restrict__ hA, bf16_t* __restrict__ hB,
                          bf16_t* __restrict__ hfin,
                          const bf16_t* wL, bf16_t* pk, unsigned* bar,
                          float* cst, const float4* bq,
                          int bgrp, int msub, int tid, int lane,
                          int mw, int nw, int lr, int lq)
{
    const unsigned fo = (unsigned)(nw * 5 * 512 + lane * 8);   // per-lane frag offset

#pragma unroll 1
    for (int t = 0; t < TSEQ; ++t) {
        const bf16_t* hsB = (t & 1) ? hB : hA;
        bf16_t*       hwB = (t & 1) ? hA : hB;
#pragma unroll
        for (int d = 0; d < 2; ++d) {
            unsigned* flags = bar + (d * 16 + bgrp) * 256;
            if (t > 0) batch_wait16(flags, (unsigned)t, lane);
            if (FAST)                                  // L1 flash-inv: stale h lines
                asm volatile("buffer_inv sc0" ::: "memory");

            const int tx = d ? (TSEQ - 1 - t) : t;
            const bf16_t* xp = xBf + (size_t)(bgrp * TSEQ + tx) * SLABX + fo;
            const bf16_t* hp = hsB + (size_t)(d * NBGRP + bgrp) * SLABH + fo;
            const bf16_t* wp = wL + (size_t)((d * 4 + mw * 2) * 12) * 512 + lane * 8;

            f32x4 acc[2][5] = {};
            // x-part: K=0..127
#pragma unroll
            for (int c = 0; c < 4; ++c) {
                bf16x8 b[5];
#pragma unroll
                for (int nf = 0; nf < 5; ++nf)
                    b[nf] = *(const bf16x8*)(xp + nf * 512);
                bf16x8 a0 = *(const bf16x8*)(wp + (0 * 12 + c) * 512);
                bf16x8 a1 = *(const bf16x8*)(wp + (1 * 12 + c) * 512);
#pragma unroll
                for (int nf = 0; nf < 5; ++nf) {
                    acc[0][nf] = __builtin_amdgcn_mfma_f32_16x16x32_bf16(a0, b[nf], acc[0][nf], 0, 0, 0);
                    acc[1][nf] = __builtin_amdgcn_mfma_f32_16x16x32_bf16(a1, b[nf], acc[1][nf], 0, 0, 0);
                }
                xp += CH;
            }
            // h-part: K=128..383
#pragma unroll
            for (int c = 0; c < 8; ++c) {
                bf16x8 b[5];
#pragma unroll
                for (int nf = 0; nf < 5; ++nf) {
                    const bf16_t* src = hp + nf * 512;
                    if (FAST) {
                        b[nf] = *(const bf16x8*)src;   // local-XCD L2 hit
                    } else {
                        union { u64 q[2]; bf16x8 v; } u;
                        u.q[0] = __hip_atomic_load((const u64*)src,       __ATOMIC_RELAXED, __HIP_MEMORY_SCOPE_AGENT);
                        u.q[1] = __hip_atomic_load((const u64*)(src + 4), __ATOMIC_RELAXED, __HIP_MEMORY_SCOPE_AGENT);
                        b[nf] = u.v;
                    }
                }
                bf16x8 a0 = *(const bf16x8*)(wp + (0 * 12 + 4 + c) * 512);
                bf16x8 a1 = *(const bf16x8*)(wp + (1 * 12 + 4 + c) * 512);
#pragma unroll
                for (int nf = 0; nf < 5; ++nf) {
                    acc[0][nf] = __builtin_amdgcn_mfma_f32_16x16x32_bf16(a0, b[nf], acc[0][nf], 0, 0, 0);
                    acc[1][nf] = __builtin_amdgcn_mfma_f32_16x16x32_bf16(a1, b[nf], acc[1][nf], 0, 0, 0);
                }
                hp += CH;
            }

            if (t < TSEQ - 1) {
                // gates -> pack (pk[d]); r13 epilogue
#pragma unroll
                for (int m = 0; m < 2; ++m) {
                    float4 bb = bq[d * 2 + m];
#pragma unroll
                    for (int nf = 0; nf < 5; ++nf) {
                        f32x4 g = acc[m][nf];
                        float gi = fsig(g[0] + bb.x);
                        float gf = fsig(g[1] + bb.y);
                        float gz = ftanh(g[2] + bb.z);
                        float go = fsig(g[3] + bb.w);
                        float cn = gf * cst[d * 10 + m * 5 + nf] + gi * gz;
                        cst[d * 10 + m * 5 + nf] = cn;
                        pk[d * 5120 + (nw * 5 + nf) * 256 + (mw * 16 + lr) * 8 + m * 4 + lq]
                            = (bf16_t)(go * ftanh(cn));
                    }
                }
                __syncthreads();                       // pack complete
                // coalesced copy pk[d] (10KB) -> producer's strip of the slab
                bf16_t* dstb = hwB + (size_t)(d * NBGRP + bgrp) * SLABH;
                for (int i = tid; i < 640; i += 512) {
                    int seg = i >> 5, off = i & 31;
                    uint4 v = *(const uint4*)(pk + d * 5120 + i * 8);
                    size_t eo = (size_t)(msub >> 1) * CH + seg * 512 + (msub & 1) * 256 + off * 8;
                    if (FAST) {
                        *(uint4*)(dstb + eo) = v;
                    } else {
                        union { uint4 q; u64 w[2]; } cv; cv.q = v;
                        __hip_atomic_store((u64*)(dstb + eo),     cv.w[0], __ATOMIC_RELAXED, __HIP_MEMORY_SCOPE_AGENT);
                        __hip_atomic_store((u64*)(dstb + eo + 4), cv.w[1], __ATOMIC_RELAXED, __HIP_MEMORY_SCOPE_AGENT);
                    }
                }
                __syncthreads();                       // all stores drained (vmcnt0 at barrier)
                if (tid == 0)
                    __hip_atomic_fetch_add(flags + msub * 16, 1u,
                        FAST ? __ATOMIC_RELAXED : __ATOMIC_RELEASE, __HIP_MEMORY_SCOPE_AGENT);
            } else {
                // final step: plain-layout hfin (kernel-boundary coherence)
#pragma unroll
                for (int m = 0; m < 2; ++m) {
                    float4 bb = bq[d * 2 + m];
                    int hid = msub * 16 + mw * 8 + m * 4 + lq;
#pragma unroll
                    for (int nf = 0; nf < 5; ++nf) {
                        f32x4 g = acc[m][nf];
                        float gi = fsig(g[0] + bb.x);
                        float gf = fsig(g[1] + bb.y);
                        float gz = ftanh(g[2] + bb.z);
                        float go = fsig(g[3] + bb.w);
                        float cn = gf * cst[d * 10 + m * 5 + nf] + gi * gz;
                        float hn = go * ftanh(cn);
                        int col = bgrp * TILE + nw * 80 + nf * 16 + lr;
                        hfin[((size_t)d * NB + col) * HSZ + hid] = (bf16_t)hn;
                    }
                }
            }
        }
    }
}

// ---- persistent LSTM: dual-dir interleave, XCD-verified fast exchange ----
// 256 blocks x 512 thr, 1 block/CU. bid = msub*16 + bgrp (msub 0..15 owns
// 64 gate rows = 16 hid of BOTH dirs). Exchange group = 16 msub-blocks
// sharing bgrp -> bid%8 = bgrp%8 -> one XCD under round-robin (verified).
__global__ __launch_bounds__(512, 1)
void lstm_persist(const bf16_t* __restrict__ Wf, const float* __restrict__ bias,
                  const bf16_t* __restrict__ xBf, const float* __restrict__ cws,
                  bf16_t* __restrict__ hA, bf16_t* __restrict__ hB,
                  bf16_t* __restrict__ hfin, unsigned* __restrict__ bar,
                  unsigned* __restrict__ xccA)
{
    __shared__ __align__(16) bf16_t wL[2 * 4 * 12 * 512];  // 96KB: both dirs' W slices
    __shared__ __align__(16) bf16_t pk[2 * 5120];          // 20KB: per-dir pack buffers
    __shared__ int sFast;

    const int bid  = blockIdx.x;
    const int msub = bid >> 4;                         // 0..15
    const int bgrp = bid & 15;
    const int tid  = threadIdx.x;
    const int wave = tid >> 6;
    const int lane = tid & 63;
    const int mw   = wave >> 2;                        // 0..1
    const int nw   = wave & 3;                         // 0..3
    const int lr   = lane & 15;
    const int lq   = lane >> 4;

    // --- stage both dirs' W slices (4 mf each) ---
    {
        uint4* wdst = (uint4*)wL;
        for (int i = tid; i < 6144; i += 512) {
            int d = i / 3072, off = i % 3072;
            const uint4* src = (const uint4*)(Wf + ((size_t)(d * 64 + msub * 4) * 12) * 512);
            wdst[d * 3072 + off] = src[off];
        }
    }
    // --- c -> registers; bias -> registers ---
    const float* cp = cws + ((size_t)bid * 512 + tid) * 20;
    float cst[20];
#pragma unroll
    for (int i = 0; i < 5; ++i) {
        float4 v = *(const float4*)(cp + i * 4);
        cst[i * 4 + 0] = v.x; cst[i * 4 + 1] = v.y;
        cst[i * 4 + 2] = v.z; cst[i * 4 + 3] = v.w;
    }
    float4 bq[4];
#pragma unroll
    for (int d = 0; d < 2; ++d)
#pragma unroll
        for (int m = 0; m < 2; ++m) {
            int hid = msub * 16 + mw * 8 + m * 4 + lq;
            bq[d * 2 + m] = *(const float4*)(bias + d * G4 + hid * 4);
        }

    unsigned* gbar = bar + 8192 + bgrp * 16;

    // --- publish XCD id, group-verify co-location (once, 16 blocks/bgrp) ---
    unsigned xcc;
    asm volatile("s_getreg_b32 %0, hwreg(HW_REG_XCC_ID)" : "=s"(xcc));
    if (tid == 0) {
        __hip_atomic_store(&xccA[bid], xcc, __ATOMIC_RELAXED, __HIP_MEMORY_SCOPE_AGENT);
        __hip_atomic_fetch_add(gbar, 1u, __ATOMIC_RELEASE, __HIP_MEMORY_SCOPE_AGENT);
        while (__hip_atomic_fetch_add(gbar, 0u, __ATOMIC_RELAXED, __HIP_MEMORY_SCOPE_AGENT) < 16u)
            __builtin_amdgcn_s_sleep(1);
        int ok = (xcc < 8u) ? 1 : 0;
        for (int m2 = 0; m2 < 16; ++m2) {
            unsigned v = __hip_atomic_load(&xccA[m2 * 16 + bgrp],
                                           __ATOMIC_RELAXED, __HIP_MEMORY_SCOPE_AGENT);
            ok &= (v == xcc) ? 1 : 0;
        }
        sFast = ok;
    }
    __syncthreads();                                   // W staged + sFast ready

    if (sFast)
        run_steps<true>(xBf, hA, hB, hfin, wL, pk, bar, cst, bq,
                        bgrp, msub, tid, lane, mw, nw, lr, lq);
    else
        run_steps<false>(xBf, hA, hB, hfin, wL, pk, bar, cst, bq,
                         bgrp, msub, tid, lane, mw, nw, lr, lq);
}

// ---- head: x_fea assembly + Linear(2560,64) + Linear(64,5) + softmax ----
__global__ __launch_bounds__(256)
void head_kernel(const bf16_t* __restrict__ hfin, const float* __restrict__ W1T,
                 const float* __restrict__ b1, const float* __restrict__ W2,
                 const float* __restrict__ b2, float* __restrict__ out)
{
    __shared__ float flat_s[2560];
    __shared__ float partial[4][64];
    __shared__ float zs[64];
    __shared__ float ls[5];
    __shared__ float es[5];
    int b = blockIdx.x, tid = threadIdx.x;
    const bf16_t* hF = hfin;
    const bf16_t* hB = hfin + (size_t)NB * HSZ;
    float* xfea = out + BATCH * 5 + (size_t)b * 2560;

    for (int j = tid; j < 2560; j += 256) {
        int s = j >> 8, c = j & 255;
        int n = b * 10 + s;
        float v = (c < 128) ? (float)hF[(size_t)n * HSZ + c] : (float)hB[(size_t)n * HSZ + c];
        flat_s[j] = v;
        xfea[j] = v;
    }
    __syncthreads();
    int j = tid & 63, q = tid >> 6;
    float sum = 0.0f;
    for (int k = q * 640; k < (q + 1) * 640; ++k) sum += flat_s[k] * W1T[k * 64 + j];
    partial[q][j] = sum;
    __syncthreads();
    if (tid < 64) zs[tid] = partial[0][tid] + partial[1][tid] + partial[2][tid] + partial[3][tid] + b1[tid];
    __syncthreads();
    if (tid < 5) {
        float l = b2[tid];
        for (int k = 0; k < 64; ++k) l += zs[k] * W2[tid * 64 + k];
        ls[tid] = l;
    }
    __syncthreads();
    if (tid < 5) {
        float m = ls[0];
        for (int k = 1; k < 5; ++k) m = fmaxf(m, ls[k]);
        es[tid] = __expf(ls[tid] - m);
    }
    __syncthreads();
    if (tid < 5) {
        float s5 = es[0] + es[1] + es[2] + es[3] + es[4];
        out[b * 5 + tid] = es[tid] / s5;
    }
}

extern "C" void kernel_launch(void* const* d_in, const int* in_sizes, int n_in,
                              void* d_out, int out_size, void* d_ws, size_t ws_size,
                              hipStream_t stream) {
    const float* x     = (const float*)d_in[0];
    const float* h0    = (const float*)d_in[1];
    const float* c0    = (const float*)d_in[2];
    const float* Wih_f = (const float*)d_in[3];
    const float* Whh_f = (const float*)d_in[4];
    const float* bih_f = (const float*)d_in[5];
    const float* bhh_f = (const float*)d_in[6];
    const float* Wih_b = (const float*)d_in[7];
    const float* Whh_b = (const float*)d_in[8];
    const float* bih_b = (const float*)d_in[9];
    const float* bhh_b = (const float*)d_in[10];
    const float* W1    = (const float*)d_in[11];
    const float* b1    = (const float*)d_in[12];
    const float* W2    = (const float*)d_in[13];
    const float* b2    = (const float*)d_in[14];
    float* out = (float*)d_out;

    uintptr_t ws = (uintptr_t)d_ws;
    bf16_t*   Wf   = (bf16_t*)(ws);                    // 1,572,864
    float*    bias = (float*)(ws + 1572864);           // 8,192
    bf16_t*   xBf  = (bf16_t*)(ws + 1581056);          // 39,321,600
    bf16_t*   hAb  = (bf16_t*)(ws + 40902656);         // 5,242,880
    bf16_t*   hBb  = (bf16_t*)(ws + 46145536);         // 5,242,880
    bf16_t*   hfin = (bf16_t*)(ws + 51388416);         // 5,242,880
    float*    W1T  = (float*)(ws + 56631296);          // 655,360
    float*    cws  = (float*)(ws + 57286656);          // 10,485,760
    unsigned* bar  = (unsigned*)(ws + 67772416);       // 40KB (flags 32KB + verify)
    unsigned* xccA = (unsigned*)(ws + 67813376);       // 1,024 (256 u32)

    hipMemsetAsync((void*)bar, 0, 40960, stream);

    prep_weights<<<(2 * G4 * 384 + 255) / 256, 256, 0, stream>>>(
        Wih_f, Whh_f, bih_f, bhh_f, Wih_b, Whh_b, bih_b, bhh_b, Wf, bias);
    prep_x<<<(NBGRP * TSEQ * SLABX + 255) / 256, 256, 0, stream>>>(x, xBf);
    prep_state<<<(2 * NBGRP * SLABH + 255) / 256, 256, 0, stream>>>(h0, hAb);
    prep_c<<<(256 * 512 * 20 + 255) / 256, 256, 0, stream>>>(c0, cws);
    prep_w1t<<<(2560 * 64 + 255) / 256, 256, 0, stream>>>(W1, W1T);

    lstm_persist<<<256, 512, 0, stream>>>(Wf, bias, xBf, cws, hAb, hBb, hfin, bar, xccA);
    head_kernel<<<BATCH, 256, 0, stream>>>(hfin, W1T, b1, W2, b2, out);
}

// Round 20
// 447.249 us; speedup vs baseline: 1.5520x; 1.2822x over previous
//
#include <hip/hip_runtime.h>

typedef __bf16 bf16_t;
typedef __bf16 bf16x8 __attribute__((ext_vector_type(8)));
typedef float f32x4 __attribute__((ext_vector_type(4)));
typedef unsigned long long u64;

#define TSEQ 30
#define ISZ  100
#define HSZ  256
#define NB   5120        // LSTM batch
#define BATCH 512
#define G4   1024        // 4*H
#define TILE 320         // batch cols per block
#define NBGRP 16
#define CH   10240       // elements per K=32 chunk panel: 20 nblk * 512
#define SLABX (4 * CH)   // x slab per (bgrp,t): K=128
#define SLABH (8 * CH)   // h slab per (dir,bgrp): K=256

__device__ __forceinline__ float fsig(float x)  { return 1.0f / (1.0f + __expf(-x)); }
__device__ __forceinline__ float ftanh(float x) { return 2.0f / (1.0f + __expf(-2.0f * x)) - 1.0f; }

// ---- prep: weights -> MFMA-fragment layout, fold biases ------------------
__global__ void prep_weights(const float* __restrict__ Wih_f, const float* __restrict__ Whh_f,
                             const float* __restrict__ bih_f, const float* __restrict__ bhh_f,
                             const float* __restrict__ Wih_b, const float* __restrict__ Whh_b,
                             const float* __restrict__ bih_b, const float* __restrict__ bhh_b,
                             bf16_t* __restrict__ Wf, float* __restrict__ bias)
{
    int idx = blockIdx.x * 256 + threadIdx.x;          // over 2*1024*384
    if (idx >= 2 * G4 * 384) return;
    int d = idx / (G4 * 384);
    int r = (idx / 384) % G4;
    int k = idx % 384;
    int h = r >> 2, gate = r & 3;
    int grow = gate * HSZ + h;
    const float* Wih = d ? Wih_b : Wih_f;
    const float* Whh = d ? Whh_b : Whh_f;
    float v;
    if (k < ISZ)       v = Wih[grow * ISZ + k];
    else if (k < 128)  v = 0.0f;
    else               v = Whh[grow * HSZ + (k - 128)];
    int mf = r >> 4, lr = r & 15;
    int ks = k >> 5, lq = (k >> 3) & 3, e = k & 7;
    size_t o = ((((size_t)d * 64 + mf) * 12 + ks) * 64 + lq * 16 + lr) * 8 + e;
    Wf[o] = (bf16_t)v;
    if (k == 0) {
        const float* bih = d ? bih_b : bih_f;
        const float* bhh = d ? bhh_b : bhh_f;
        bias[d * G4 + r] = bih[grow] + bhh[grow];
    }
}

// ---- prep: x -> fragment layout, chunk-contiguous ------------------------
__global__ void prep_x(const float* __restrict__ x, bf16_t* __restrict__ xBf)
{
    int idx = blockIdx.x * 256 + threadIdx.x;          // over 16*30*4*20*512
    if (idx >= NBGRP * TSEQ * SLABX) return;
    int e    = idx & 7;
    int lane = (idx >> 3) & 63;
    int i2   = idx >> 9;
    int nblk = i2 % 20; i2 /= 20;
    int ks   = i2 & 3;  i2 >>= 2;
    int t    = i2 % TSEQ;
    int bgrp = i2 / TSEQ;
    int n = bgrp * TILE + nblk * 16 + (lane & 15);
    int k = ks * 32 + (lane >> 4) * 8 + e;
    float v = (k < ISZ) ? x[(size_t)n * (TSEQ * ISZ) + t * ISZ + k] : 0.0f;
    xBf[idx] = (bf16_t)v;
}

// ---- prep: h0 -> fragment layout ping buffer -----------------------------
__global__ void prep_state(const float* __restrict__ h0, bf16_t* __restrict__ hA)
{
    int idx = blockIdx.x * 256 + threadIdx.x;          // over 2*16*8*20*512
    if (idx >= 2 * NBGRP * SLABH) return;
    int e    = idx & 7;
    int lane = (idx >> 3) & 63;
    int i2   = idx >> 9;
    int nblk = i2 % 20; i2 /= 20;
    int ksh  = i2 & 7;  i2 >>= 3;
    int bgrp = i2 & 15;
    int dir  = i2 >> 4;
    int col = bgrp * TILE + nblk * 16 + (lane & 15);
    int hid = ksh * 32 + (lane >> 4) * 8 + e;
    hA[idx] = (bf16_t)h0[((size_t)dir * NB + col) * HSZ + hid];
}

// ---- prep: c0 -> per-thread-contiguous layout ----------------------------
__global__ void prep_c(const float* __restrict__ c0, float* __restrict__ cws)
{
    int idx = blockIdx.x * 256 + threadIdx.x;          // over 256*512*20
    if (idx >= 256 * 512 * 20) return;
    int m   = idx & 3;
    int nf  = (idx >> 2) % 5;
    int tid = (idx / 20) & 511;
    int bid = idx / (20 * 512);
    int msub = bid >> 5, dir = (bid >> 4) & 1, bgrp = bid & 15;
    int lane = tid & 63, mw = (tid >> 6) >> 2, nw = (tid >> 6) & 3;
    int lr = lane & 15, lq = lane >> 4;
    int col = bgrp * TILE + nw * 80 + nf * 16 + lr;
    int hid = msub * 32 + mw * 16 + m * 4 + lq;
    cws[idx] = c0[((size_t)dir * NB + col) * HSZ + hid];
}

// ---- prep: transpose W1 for coalesced head ------------------------------
__global__ void prep_w1t(const float* __restrict__ W1, float* __restrict__ W1T)
{
    int idx = blockIdx.x * 256 + threadIdx.x;          // over 2560*64
    if (idx >= 2560 * 64) return;
    int k = idx / 64, j = idx % 64;
    W1T[k * 64 + j] = W1[j * 2560 + k];
}

// ---- the 30-step loop, templated on exchange path ------------------------
// FAST (group verified co-XCD): plain h stores (dirty local L2), plain h
// loads (hit local L2), RELAXED RMW barrier, buffer_inv sc0 (L1-only) per
// step. SLOW (any mapping): r12-proven MALL-coherent 8B atomics + RELEASE.
// Both: B direct-to-register (fragment layout -> perfectly coalesced bf16x8
// loads), NO LDS staging of B, minimal barriers (2/step, epilogue only).
template<bool FAST>
__device__ void run_steps(const bf16_t* __restrict__ xBf,
                          bf16_t* __restrict__ hA, bf16_t* __restrict__ hB,
                          bf16_t* __restrict__ hfin,
                          const bf16_t* wL, bf16_t* pkL, unsigned* mybar,
                          f32x4* c4, const float4* bq,
                          int dir, int bgrp, int msub,
                          int tid, int lane, int mw, int nw, int lr, int lq)
{
#pragma unroll 1
    for (int t = 0; t < TSEQ; ++t) {
        const bf16_t* hs = (t & 1) ? hB : hA;
        bf16_t*       hw = (t & 1) ? hA : hB;
        const int tx = dir ? (TSEQ - 1 - t) : t;
        const bf16_t* xsl = xBf + (size_t)(bgrp * TSEQ + tx) * SLABX + nw * 5 * 512 + lane * 8;
        const bf16_t* hsl = hs + (size_t)(dir * NBGRP + bgrp) * SLABH + nw * 5 * 512 + lane * 8;

        f32x4 acc[4][5] = {};
        // --- x chunks (K=0..127): plain L2-cached loads ---
#pragma unroll
        for (int c = 0; c < 4; ++c) {
            bf16x8 b[5];
#pragma unroll
            for (int nf = 0; nf < 5; ++nf)
                b[nf] = *(const bf16x8*)(xsl + (size_t)c * CH + nf * 512);
            bf16x8 a[4];
#pragma unroll
            for (int m = 0; m < 4; ++m)
                a[m] = *(const bf16x8*)(wL + ((mw * 4 + m) * 12 + c) * 512 + lane * 8);
#pragma unroll
            for (int m = 0; m < 4; ++m)
#pragma unroll
                for (int nf = 0; nf < 5; ++nf)
                    acc[m][nf] = __builtin_amdgcn_mfma_f32_16x16x32_bf16(a[m], b[nf], acc[m][nf], 0, 0, 0);
        }
        // --- h chunks (K=128..383) ---
#pragma unroll
        for (int c = 4; c < 12; ++c) {
            bf16x8 b[5];
#pragma unroll
            for (int nf = 0; nf < 5; ++nf) {
                const bf16_t* src = hsl + (size_t)(c - 4) * CH + nf * 512;
                if (FAST) {
                    b[nf] = *(const bf16x8*)src;       // local-XCD L2 hit
                } else {
                    union { u64 q[2]; bf16x8 v; } u;
                    u.q[0] = __hip_atomic_load((const u64*)src,       __ATOMIC_RELAXED, __HIP_MEMORY_SCOPE_AGENT);
                    u.q[1] = __hip_atomic_load((const u64*)(src + 4), __ATOMIC_RELAXED, __HIP_MEMORY_SCOPE_AGENT);
                    b[nf] = u.v;
                }
            }
            bf16x8 a[4];
#pragma unroll
            for (int m = 0; m < 4; ++m)
                a[m] = *(const bf16x8*)(wL + ((mw * 4 + m) * 12 + c) * 512 + lane * 8);
#pragma unroll
            for (int m = 0; m < 4; ++m)
#pragma unroll
                for (int nf = 0; nf < 5; ++nf)
                    acc[m][nf] = __builtin_amdgcn_mfma_f32_16x16x32_bf16(a[m], b[nf], acc[m][nf], 0, 0, 0);
        }

        // --- gates + state update ---
        if (t < TSEQ - 1) {
#pragma unroll
            for (int m = 0; m < 4; ++m) {
                float4 bb = bq[m];
                int hl = mw * 16 + m * 4 + lq;
#pragma unroll
                for (int nf = 0; nf < 5; ++nf) {
                    f32x4 g = acc[m][nf];
                    float gi = fsig(g[0] + bb.x);
                    float gf = fsig(g[1] + bb.y);
                    float gz = ftanh(g[2] + bb.z);
                    float go = fsig(g[3] + bb.w);
                    float cn = gf * c4[nf][m] + gi * gz;
                    c4[nf][m] = cn;
                    pkL[(nw * 5 + nf) * 512 + ((hl >> 3) * 16 + lr) * 8 + (hl & 7)]
                        = (bf16_t)(go * ftanh(cn));
                }
            }
            __syncthreads();                           // pack complete
            bf16_t* dstb = hw + (size_t)(dir * NBGRP + bgrp) * SLABH + (size_t)msub * 20 * 512;
            if (FAST) {
                uint4* dst = (uint4*)dstb;
                const uint4* src = (const uint4*)pkL;
                for (int i = tid; i < 1280; i += 512) dst[i] = src[i];
            } else {
                u64* dst = (u64*)dstb;
                const u64* src = (const u64*)pkL;
                for (int i = tid; i < 2560; i += 512)
                    __hip_atomic_store(&dst[i], src[i], __ATOMIC_RELAXED, __HIP_MEMORY_SCOPE_AGENT);
            }
            __syncthreads();                           // stores drained (vmcnt0 at barrier)
            if (tid == 0) {
                __hip_atomic_fetch_add(mybar, 1u,
                    FAST ? __ATOMIC_RELAXED : __ATOMIC_RELEASE, __HIP_MEMORY_SCOPE_AGENT);
                while (__hip_atomic_fetch_add(mybar, 0u, __ATOMIC_RELAXED, __HIP_MEMORY_SCOPE_AGENT)
                       < 8u * (unsigned)(t + 2))
                    __builtin_amdgcn_s_sleep(1);
            }
            __syncthreads();                           // whole block sees barrier passed
            if (FAST)                                  // flash-inv per-CU L1 (h lines may be stale)
                asm volatile("buffer_inv sc0" ::: "memory");
        } else {
            // final step: plain-layout hfin (kernel-boundary coherence for head)
#pragma unroll
            for (int m = 0; m < 4; ++m) {
                float4 bb = bq[m];
#pragma unroll
                for (int nf = 0; nf < 5; ++nf) {
                    f32x4 g = acc[m][nf];
                    float gi = fsig(g[0] + bb.x);
                    float gf = fsig(g[1] + bb.y);
                    float gz = ftanh(g[2] + bb.z);
                    float go = fsig(g[3] + bb.w);
                    float cn = gf * c4[nf][m] + gi * gz;
                    float hn = go * ftanh(cn);
                    int col = bgrp * TILE + nw * 80 + nf * 16 + lr;
                    int hid = msub * 32 + mw * 16 + m * 4 + lq;
                    hfin[((size_t)dir * NB + col) * HSZ + hid] = (bf16_t)hn;
                }
            }
        }
    }
}

// ---- persistent LSTM: XCD-verified fast exchange -------------------------
// 256 blocks x 512 thr, 1 block/CU. bid = msub*32 + dir*16 + bgrp; the 8
// group members share bid%8 -> one XCD under round-robin. Verified at
// runtime via HW_REG_XCC_ID; mismatch -> r12-proven coherent slow path.
__global__ __launch_bounds__(512, 1)
void lstm_persist(const bf16_t* __restrict__ Wf, const float* __restrict__ bias,
                  const bf16_t* __restrict__ xBf, const float* __restrict__ cws,
                  bf16_t* __restrict__ hA, bf16_t* __restrict__ hB,
                  bf16_t* __restrict__ hfin, unsigned* __restrict__ bar,
                  unsigned* __restrict__ xccA)
{
    __shared__ __align__(16) bf16_t wL[8 * 12 * 512];  // 96KB W slice
    __shared__ __align__(16) bf16_t pkL[CH];           // 20KB h pack buffer
    __shared__ int sFast;

    const int bid  = blockIdx.x;
    const int msub = bid >> 5;
    const int dir  = (bid >> 4) & 1;
    const int bgrp = bid & 15;
    const int tid  = threadIdx.x;
    const int lane = tid & 63;
    const int mw   = (tid >> 6) >> 2;                  // 0..1
    const int nw   = (tid >> 6) & 3;                   // 0..3
    const int lr   = lane & 15;
    const int lq   = lane >> 4;

    // --- stage W slice once; c -> registers; bias -> registers ---
    {
        const uint4* wsrc = (const uint4*)(Wf + ((size_t)dir * 64 + msub * 8) * 12 * 512);
        uint4* wdst = (uint4*)wL;
        for (int i = tid; i < 6144; i += 512) wdst[i] = wsrc[i];
    }
    const float* cp = cws + ((size_t)bid * 512 + tid) * 20;
    f32x4 c4[5];
#pragma unroll
    for (int nf = 0; nf < 5; ++nf) c4[nf] = *(const f32x4*)(cp + nf * 4);
    float4 bq[4];
#pragma unroll
    for (int m = 0; m < 4; ++m)
        bq[m] = *(const float4*)(bias + dir * G4 + (msub * 32 + mw * 16 + m * 4 + lq) * 4);

    unsigned* mybar = bar + (dir * NBGRP + bgrp) * 16; // 64B-spaced counters

    // --- publish XCD id, group-verify co-location (once) ---
    unsigned xcc;
    asm volatile("s_getreg_b32 %0, hwreg(HW_REG_XCC_ID)" : "=s"(xcc));
    if (tid == 0) {
        __hip_atomic_store(&xccA[bid], xcc, __ATOMIC_RELAXED, __HIP_MEMORY_SCOPE_AGENT);
        __hip_atomic_fetch_add(mybar, 1u, __ATOMIC_RELEASE, __HIP_MEMORY_SCOPE_AGENT);
        while (__hip_atomic_fetch_add(mybar, 0u, __ATOMIC_RELAXED, __HIP_MEMORY_SCOPE_AGENT) < 8u)
            __builtin_amdgcn_s_sleep(1);
        int ok = (xcc < 8u) ? 1 : 0;
        for (int m2 = 0; m2 < 8; ++m2) {
            unsigned v = __hip_atomic_load(&xccA[m2 * 32 + dir * 16 + bgrp],
                                           __ATOMIC_RELAXED, __HIP_MEMORY_SCOPE_AGENT);
            ok &= (v == xcc) ? 1 : 0;
        }
        sFast = ok;
    }
    __syncthreads();

    if (sFast)
        run_steps<true>(xBf, hA, hB, hfin, wL, pkL, mybar, c4, bq,
                        dir, bgrp, msub, tid, lane, mw, nw, lr, lq);
    else
        run_steps<false>(xBf, hA, hB, hfin, wL, pkL, mybar, c4, bq,
                         dir, bgrp, msub, tid, lane, mw, nw, lr, lq);
}

// ---- head: x_fea assembly + Linear(2560,64) + Linear(64,5) + softmax ----
__global__ __launch_bounds__(256)
void head_kernel(const bf16_t* __restrict__ hfin, const float* __restrict__ W1T,
                 const float* __restrict__ b1, const float* __restrict__ W2,
                 const float* __restrict__ b2, float* __restrict__ out)
{
    __shared__ float flat_s[2560];
    __shared__ float partial[4][64];
    __shared__ float zs[64];
    __shared__ float ls[5];
    __shared__ float es[5];
    int b = blockIdx.x, tid = threadIdx.x;
    const bf16_t* hF = hfin;
    const bf16_t* hB = hfin + (size_t)NB * HSZ;
    float* xfea = out + BATCH * 5 + (size_t)b * 2560;

    for (int j = tid; j < 2560; j += 256) {
        int s = j >> 8, c = j & 255;
        int n = b * 10 + s;
        float v = (c < 128) ? (float)hF[(size_t)n * HSZ + c] : (float)hB[(size_t)n * HSZ + c];
        flat_s[j] = v;
        xfea[j] = v;
    }
    __syncthreads();
    int j = tid & 63, q = tid >> 6;
    float sum = 0.0f;
    for (int k = q * 640; k < (q + 1) * 640; ++k) sum += flat_s[k] * W1T[k * 64 + j];
    partial[q][j] = sum;
    __syncthreads();
    if (tid < 64) zs[tid] = partial[0][tid] + partial[1][tid] + partial[2][tid] + partial[3][tid] + b1[tid];
    __syncthreads();
    if (tid < 5) {
        float l = b2[tid];
        for (int k = 0; k < 64; ++k) l += zs[k] * W2[tid * 64 + k];
        ls[tid] = l;
    }
    __syncthreads();
    if (tid < 5) {
        float m = ls[0];
        for (int k = 1; k < 5; ++k) m = fmaxf(m, ls[k]);
        es[tid] = __expf(ls[tid] - m);
    }
    __syncthreads();
    if (tid < 5) {
        float s5 = es[0] + es[1] + es[2] + es[3] + es[4];
        out[b * 5 + tid] = es[tid] / s5;
    }
}

extern "C" void kernel_launch(void* const* d_in, const int* in_sizes, int n_in,
                              void* d_out, int out_size, void* d_ws, size_t ws_size,
                              hipStream_t stream) {
    const float* x     = (const float*)d_in[0];
    const float* h0    = (const float*)d_in[1];
    const float* c0    = (const float*)d_in[2];
    const float* Wih_f = (const float*)d_in[3];
    const float* Whh_f = (const float*)d_in[4];
    const float* bih_f = (const float*)d_in[5];
    const float* bhh_f = (const float*)d_in[6];
    const float* Wih_b = (const float*)d_in[7];
    const float* Whh_b = (const float*)d_in[8];
    const float* bih_b = (const float*)d_in[9];
    const float* bhh_b = (const float*)d_in[10];
    const float* W1    = (const float*)d_in[11];
    const float* b1    = (const float*)d_in[12];
    const float* W2    = (const float*)d_in[13];
    const float* b2    = (const float*)d_in[14];
    float* out = (float*)d_out;

    uintptr_t ws = (uintptr_t)d_ws;
    bf16_t*   Wf   = (bf16_t*)(ws);                    // 1,572,864
    float*    bias = (float*)(ws + 1572864);           // 8,192
    bf16_t*   xBf  = (bf16_t*)(ws + 1581056);          // 39,321,600
    bf16_t*   hAb  = (bf16_t*)(ws + 40902656);         // 5,242,880
    bf16_t*   hBb  = (bf16_t*)(ws + 46145536);         // 5,242,880
    bf16_t*   hfin = (bf16_t*)(ws + 51388416);         // 5,242,880
    float*    W1T  = (float*)(ws + 56631296);          // 655,360
    float*    cws  = (float*)(ws + 57286656);          // 10,485,760
    unsigned* bar  = (unsigned*)(ws + 67772416);       // 2,048 (32 groups x 64B)
    unsigned* xccA = (unsigned*)(ws + 67774464);       // 1,024 (256 u32)

    hipMemsetAsync((void*)bar, 0, 4096, stream);

    prep_weights<<<(2 * G4 * 384 + 255) / 256, 256, 0, stream>>>(
        Wih_f, Whh_f, bih_f, bhh_f, Wih_b, Whh_b, bih_b, bhh_b, Wf, bias);
    prep_x<<<(NBGRP * TSEQ * SLABX + 255) / 256, 256, 0, stream>>>(x, xBf);
    prep_state<<<(2 * NBGRP * SLABH + 255) / 256, 256, 0, stream>>>(h0, hAb);
    prep_c<<<(256 * 512 * 20 + 255) / 256, 256, 0, stream>>>(c0, cws);
    prep_w1t<<<(2560 * 64 + 255) / 256, 256, 0, stream>>>(W1, W1T);

    lstm_persist<<<256, 512, 0, stream>>>(Wf, bias, xBf, cws, hAb, hBb, hfin, bar, xccA);
    head_kernel<<<BATCH, 256, 0, stream>>>(hfin, W1T, b1, W2, b2, out);
}